// Round 5
// baseline (211.290 us; speedup 1.0000x reference)
//
#include <hip/hip_runtime.h>
#include <hip/hip_bf16.h>

// Problem constants
#define N_ROWS 8192
#define D_DIM  1024
#define HALF_N 4096
#define N_TILES 2080             // 64*65/2 upper-triangular 128x128 tile pairs
#define N_RED  8                 // parallel loss-reduction blocks
constexpr float INV_T = 1.0f / 0.07f;   // 14.2857143 — also the fixed softmax max M

typedef __attribute__((ext_vector_type(4)))  float f32x4;
typedef __attribute__((ext_vector_type(16))) float f32x16;
typedef __attribute__((ext_vector_type(4)))  int   i32x4;
typedef __attribute__((ext_vector_type(8)))  int   i32x8;

// async global->LDS, 16B/lane. LDS dest is wave-uniform base + lane*16.
__device__ __forceinline__ void async_ld16(const void* g, void* lds) {
    __builtin_amdgcn_global_load_lds(
        (const __attribute__((address_space(1))) void*)g,
        (__attribute__((address_space(3))) void*)lds,
        16, 0, 0);
}

// pack 4 floats -> 4 OCP e4m3 bytes in one dword
__device__ __forceinline__ unsigned int pk_fp8x4(float a, float b, float c, float d) {
    int v = __builtin_amdgcn_cvt_pk_fp8_f32(a, b, 0, false);   // bytes 0,1
    v = __builtin_amdgcn_cvt_pk_fp8_f32(c, d, v, true);        // bytes 2,3
    return (unsigned int)v;
}

// two b128 LDS reads (slot s and s^1 of the same 64B row-half) -> one v8i32
// MX fragment (32 contiguous K-bytes / lane)
__device__ __forceinline__ i32x8 ld_frag(const unsigned char* p, int lo) {
    i32x4 L = *(const i32x4*)(p + lo);
    i32x4 H = *(const i32x4*)(p + (lo ^ 16));
    i32x8 r;
    r[0] = L[0]; r[1] = L[1]; r[2] = L[2]; r[3] = L[3];
    r[4] = H[0]; r[5] = H[1]; r[6] = H[2]; r[7] = H[3];
    return r;
}

// MX-scaled fp8 MFMA, scales fixed at e8m0 0x7F = 2^0 = 1.0 (exact fp8 product,
// 2x the non-scaled fp8 rate). fmtA=fmtB=0 (OCP e4m3). Validated r21 (passed).
#define MXMFMA(AF, BF, ACC) ACC = __builtin_amdgcn_mfma_scale_f32_32x32x64_f8f6f4( \
        AF, BF, ACC, 0, 0, 0, 0x7F7F7F7F, 0, 0x7F7F7F7F)

// ---------------------------------------------------------------------------
// Kernel 1: row norms + fp8 e4m3 normalized copy + zeroing of row_sum and the
// handshake cells. One wave per row. (unchanged — measured fine)
__global__ __launch_bounds__(256) void norm_kernel(const float* __restrict__ feat,
                                                   unsigned char* __restrict__ fn8,
                                                   float* __restrict__ row_sum,
                                                   unsigned int* __restrict__ done_cnt,
                                                   unsigned int* __restrict__ fin_cnt,
                                                   float* __restrict__ loss_acc) {
    const int w = threadIdx.x >> 6, lane = threadIdx.x & 63;
    const int row = blockIdx.x * 4 + w;
    if (blockIdx.x == 0 && threadIdx.x == 0) {
        *done_cnt = 0u;
        *fin_cnt = 0u;
        *loss_acc = 0.f;
    }
    const float4* src = (const float4*)(feat + (size_t)row * D_DIM);
    float4 v[4];
    float ss = 0.f;
#pragma unroll
    for (int t = 0; t < 4; ++t) {
        v[t] = src[lane + 64 * t];
        ss += v[t].x * v[t].x + v[t].y * v[t].y + v[t].z * v[t].z + v[t].w * v[t].w;
    }
#pragma unroll
    for (int off = 32; off; off >>= 1) ss += __shfl_xor(ss, off);
    float nrm = fmaxf(sqrtf(ss), 1e-8f);
    if (lane == 0) row_sum[row] = 0.f;
    const float inv = 1.0f / nrm;
    unsigned int* dst = (unsigned int*)(fn8 + (size_t)row * D_DIM);
#pragma unroll
    for (int t = 0; t < 4; ++t)
        dst[lane + 64 * t] = pk_fp8x4(v[t].x * inv, v[t].y * inv, v[t].z * inv, v[t].w * inv);
}

// ---------------------------------------------------------------------------
// Raw workgroup barrier WITHOUT the __syncthreads() vmcnt(0) drain.
#define BARRIER() do { asm volatile("" ::: "memory"); \
    __builtin_amdgcn_s_barrier();                      \
    asm volatile("" ::: "memory"); } while (0)

// ---------------------------------------------------------------------------
// Kernel 2 (r22): MX-fp8 128x128 triangular GEMM, two fixes over r21:
//
// 1. CONFLICT-FREE LDS LAYOUT (r21 measured exactly 4 extra cyc on every
//    ds_read_b128 = 4.26M conflict-cycles): per 32-row x 128B chunk,
//      offset(r, u) = r*64 + (u>>2)*2048 + ((u&3) ^ ((r>>1)&3))*16
//    (64B rows, 4-slot rotation keyed by (r>>1)&3 — the r16 pattern class
//    that measured 0 conflicts: every 8 consecutive lanes of a b128 read
//    cover all 32 banks exactly once).
//    Staged via linear global_load_lds dest + pre-swizzled per-lane source:
//    call c writes row (c&1)*16 + (l>>2), unit u = (c>>1)*4 + ((l&3)^((l>>3)&3)).
//    Fragment read: lane (fr,h) reads slots (2h)^fkey and its ^1 partner of
//    half-row k64 -> K-bytes [64*k64+32h, +32) — identical semantics to r21.
//
// 2. ISSUE-EARLY / WAIT-LATE ring-2 (r21 issued loads then immediately
//    drained vmcnt(0): zero intra-block overlap): stage tile kt+1 FIRST,
//    compute tile kt, THEN vmcnt(0)+barrier — loads land under the
//    ~400-500 cyc compute phase; barriers halve to 8. Race-safe: buf^1's
//    ds_reads are register-complete before this step's MFMAs, which
//    precede the barrier.
//
// Epilogue (32x32 C/D layout) + fence-free loss tail verbatim from r21.
__global__ __launch_bounds__(256) void simgemm_kernel(const unsigned char* __restrict__ fn8,
                                                      float* __restrict__ row_sum,
                                                      float* __restrict__ s_target,
                                                      unsigned int* __restrict__ done_cnt,
                                                      unsigned int* __restrict__ fin_cnt,
                                                      float* __restrict__ loss_acc,
                                                      float* __restrict__ out) {
    __shared__ __align__(16) unsigned char As[2][16 * 1024];   // 32 KiB
    __shared__ __align__(16) unsigned char Bs[2][16 * 1024];   // 32 KiB
    // triangular decode: t -> (I,J), I<=J
    const int t = blockIdx.x;
    int a = (int)((sqrtf(8.f * (float)t + 1.f) - 1.f) * 0.5f);
    while ((a + 1) * (a + 2) / 2 <= t) ++a;
    while (a * (a + 1) / 2 > t) --a;
    const int I = t - a * (a + 1) / 2;   // row-tile index (<= J)
    const int J = a;                     // col-tile index
    const int r0 = I * 128, c0 = J * 128;
    const bool isdiag = (I == J);
    const bool haspair = (J == I + 32);  // contains sim[i, i+4096] for rows in I

    const int tid = threadIdx.x;
    const int w = tid >> 6, lane = tid & 63;
    const int wr = (w >> 1) * 64;  // wave's row base within tile
    const int wc = (w & 1) * 64;   // wave's col base within tile

    // ---- staging addressing (wave w stages rows [w*32, w*32+32) of A,B) ----
    // call c (c=0..3) -> LDS chunk offset c*1024, lane l writes 16B of
    // row (c&1)*16 + (l>>2), logical unit u = (c>>1)*4 + ((l&3)^((l>>3)&3))
    const int srow2 = lane >> 2;                                   // 0..15
    const int slog2 = (((lane & 3) ^ ((lane >> 3) & 3))) * 16;     // unit byte off
    const unsigned char* pA[4];
    const unsigned char* pB[4];
#pragma unroll
    for (int c = 0; c < 4; ++c) {
        const size_t roff = (size_t)(w * 32 + (c & 1) * 16 + srow2) * D_DIM
                            + (c >> 1) * 64 + slog2;
        pA[c] = fn8 + (size_t)r0 * D_DIM + roff;
        pB[c] = fn8 + (size_t)c0 * D_DIM + roff;
    }

    // ---- fragment addressing ----
    const int fr = lane & 31;          // row (A) / col (B) within 32-chunk
    const int h = lane >> 5;           // K-half owner
    const int fkey = (fr >> 1) & 3;    // slot rotation key
    const int ca0 = ((w >> 1) * 2 + 0) * 4096 + fr * 64;
    const int ca1 = ((w >> 1) * 2 + 1) * 4096 + fr * 64;
    const int cb0 = ((w & 1) * 2 + 0) * 4096 + fr * 64;
    const int cb1 = ((w & 1) * 2 + 1) * 4096 + fr * 64;

    f32x16 acc[2][2] = {};

    // ---- prologue: stage tile 0 into buf 0 ----
#pragma unroll
    for (int c = 0; c < 4; ++c) {
        async_ld16(pA[c], &As[0][w * 4096 + c * 1024]);
        async_ld16(pB[c], &Bs[0][w * 4096 + c * 1024]);
    }
    asm volatile("s_waitcnt vmcnt(0)" ::: "memory");
    BARRIER();

    int buf = 0;
    for (int kt = 0; kt < 8; ++kt) {
        // issue-early: stage tile kt+1 into buf^1 (its last reads completed
        // before the barrier we just crossed)
        if (kt < 7) {
            const int koff = (kt + 1) * 128;
#pragma unroll
            for (int c = 0; c < 4; ++c) {
                async_ld16(pA[c] + koff, &As[buf ^ 1][w * 4096 + c * 1024]);
                async_ld16(pB[c] + koff, &Bs[buf ^ 1][w * 4096 + c * 1024]);
            }
        }
        // compute tile kt from buf (compiler manages lgkmcnt for ds->MFMA)
        const unsigned char* bA = &As[buf][0];
        const unsigned char* bB = &Bs[buf][0];
#pragma unroll
        for (int k64 = 0; k64 < 2; ++k64) {
            const int lo = k64 * 2048 + ((2 * h) ^ fkey) * 16;
            i32x8 a0 = ld_frag(bA + ca0, lo);
            i32x8 a1 = ld_frag(bA + ca1, lo);
            i32x8 b0 = ld_frag(bB + cb0, lo);
            i32x8 b1 = ld_frag(bB + cb1, lo);
            MXMFMA(a0, b0, acc[0][0]);
            MXMFMA(a0, b1, acc[0][1]);
            MXMFMA(a1, b0, acc[1][0]);
            MXMFMA(a1, b1, acc[1][1]);
        }
        // wait-late: next tile's loads had the whole compute phase to land
        if (kt < 7) {
            asm volatile("s_waitcnt vmcnt(0)" ::: "memory");
            BARRIER();
        }
        buf ^= 1;
    }

    // ---- epilogue: e = exp(sim - M); rows-in-I sums + (I<J) cols-in-J sums ----
    // 32x32 C/D layout: col = c0 + wc + tj*32 + (lane&31),
    //                   row = r0 + wr + ti*32 + (reg&3) + 8*(reg>>2) + 4*h
    const int colL = lane & 31;
    float cs[2] = {0.f, 0.f};
#pragma unroll
    for (int ti = 0; ti < 2; ++ti) {
#pragma unroll
        for (int reg = 0; reg < 16; ++reg) {
            const int rowL = (reg & 3) + 8 * (reg >> 2) + 4 * h;
            const int grow = r0 + wr + ti * 32 + rowL;
            float s = 0.f;
#pragma unroll
            for (int tj = 0; tj < 2; ++tj) {
                const int gcol = c0 + wc + tj * 32 + colL;
                float sim = acc[ti][tj][reg] * INV_T;
                float e = __expf(sim - INV_T);
                if (isdiag && grow == gcol) e = 0.f;   // diagonal mask
                if (haspair && gcol == grow + HALF_N) {
                    __hip_atomic_store(&s_target[grow], sim, __ATOMIC_RELAXED,
                                       __HIP_MEMORY_SCOPE_AGENT);
                    __hip_atomic_store(&s_target[gcol], sim, __ATOMIC_RELAXED,
                                       __HIP_MEMORY_SCOPE_AGENT);
                }
                s += e;
                cs[tj] += e;
            }
            // row path: reduce across the 32 column-lanes of this h-group
            s += __shfl_xor(s, 1);
            s += __shfl_xor(s, 2);
            s += __shfl_xor(s, 4);
            s += __shfl_xor(s, 8);
            s += __shfl_xor(s, 16);
            if (colL == 0) atomicAdd(&row_sum[grow], s);
        }
    }
    if (!isdiag) {
        // col path: lane l holds 32 of the wave's 64 rows for its column;
        // pair with lane l^32 (other h) to complete, one atomic per column
#pragma unroll
        for (int tj = 0; tj < 2; ++tj) {
            float s = cs[tj] + __shfl_xor(cs[tj], 32);
            if (h == 0) atomicAdd(&row_sum[c0 + wc + tj * 32 + colL], s);
        }
    }

    // ---- fence-free fused loss tail, 8-way parallel ----
    __syncthreads();   // all waves' vmem drained (compiler emits vmcnt(0) here)
    __shared__ unsigned int my_ord;
    if (tid == 0)
        my_ord = __hip_atomic_fetch_add(done_cnt, 1u, __ATOMIC_RELAXED,
                                        __HIP_MEMORY_SCOPE_AGENT);
    __syncthreads();
    const unsigned int ord = my_ord;
    if (ord >= N_TILES - N_RED) {
        // wait until ALL 2080 blocks have signalled (their sums are in).
        if (tid == 0) {
            while (__hip_atomic_load(done_cnt, __ATOMIC_RELAXED,
                                     __HIP_MEMORY_SCOPE_AGENT) < N_TILES)
                __builtin_amdgcn_s_sleep(1);
        }
        __syncthreads();
        const int slice = (int)(ord - (N_TILES - N_RED));   // 0..7
        const int base_row = slice * (N_ROWS / N_RED) + tid * 4;
        float rv[4], sv[4];
#pragma unroll
        for (int u = 0; u < 4; ++u) {
            rv[u] = __hip_atomic_load(&row_sum[base_row + u], __ATOMIC_RELAXED,
                                      __HIP_MEMORY_SCOPE_AGENT);
            sv[u] = __hip_atomic_load(&s_target[base_row + u], __ATOMIC_RELAXED,
                                      __HIP_MEMORY_SCOPE_AGENT);
        }
        float local = 0.f;
#pragma unroll
        for (int u = 0; u < 4; ++u)
            local += __logf(rv[u]) - sv[u];
#pragma unroll
        for (int off = 32; off; off >>= 1) local += __shfl_xor(local, off);
        __shared__ float part[4];
        if ((tid & 63) == 0) part[tid >> 6] = local;
        __syncthreads();
        if (tid == 0) {
            float bsum = part[0] + part[1] + part[2] + part[3];
            __hip_atomic_fetch_add(loss_acc, bsum, __ATOMIC_RELAXED,
                                   __HIP_MEMORY_SCOPE_AGENT);
            unsigned int f = __hip_atomic_fetch_add(fin_cnt, 1u, __ATOMIC_ACQ_REL,
                                                    __HIP_MEMORY_SCOPE_AGENT);
            if (f == N_RED - 1) {
                float accv = __hip_atomic_load(loss_acc, __ATOMIC_RELAXED,
                                               __HIP_MEMORY_SCOPE_AGENT);
                out[0] = INV_T + accv * (1.0f / N_ROWS);
            }
        }
    }
}

// ---------------------------------------------------------------------------
extern "C" void kernel_launch(void* const* d_in, const int* in_sizes, int n_in,
                              void* d_out, int out_size, void* d_ws, size_t ws_size,
                              hipStream_t stream) {
    const float* feat = (const float*)d_in[0];
    float* out = (float*)d_out;
    char* ws = (char*)d_ws;

    unsigned char* fn8 = (unsigned char*)ws;                  // 8192*1024 fp8 = 8 MiB
    size_t off = (size_t)N_ROWS * D_DIM;
    float* row_sum = (float*)(ws + off);   off += N_ROWS * sizeof(float);
    float* s_target = (float*)(ws + off);  off += N_ROWS * sizeof(float);
    unsigned int* done_cnt = (unsigned int*)(ws + off);  off += sizeof(unsigned int);
    unsigned int* fin_cnt = (unsigned int*)(ws + off);   off += sizeof(unsigned int);
    float* loss_acc = (float*)(ws + off);

    norm_kernel<<<N_ROWS / 4, 256, 0, stream>>>(feat, fn8, row_sum, done_cnt, fin_cnt, loss_acc);
    simgemm_kernel<<<N_TILES, 256, 0, stream>>>(fn8, row_sum, s_target, done_cnt, fin_cnt, loss_acc, out);
}

// Round 6
// 169.807 us; speedup vs baseline: 1.2443x; 1.2443x over previous
//
#include <hip/hip_runtime.h>
#include <hip/hip_bf16.h>

// Problem constants
#define N_ROWS 8192
#define D_DIM  1024
#define HALF_N 4096
#define N_TILES 2080             // 64*65/2 upper-triangular 128x128 tile pairs
#define N_RED  8                 // parallel loss-reduction blocks
constexpr float INV_T = 1.0f / 0.07f;   // 14.2857143 — also the fixed softmax max M

typedef __attribute__((ext_vector_type(4)))  float f32x4;
typedef __attribute__((ext_vector_type(16))) float f32x16;
typedef __attribute__((ext_vector_type(4)))  int   i32x4;
typedef __attribute__((ext_vector_type(8)))  int   i32x8;

// async global->LDS, 16B/lane. LDS dest is wave-uniform base + lane*16.
__device__ __forceinline__ void async_ld16(const void* g, void* lds) {
    __builtin_amdgcn_global_load_lds(
        (const __attribute__((address_space(1))) void*)g,
        (__attribute__((address_space(3))) void*)lds,
        16, 0, 0);
}

// pack 4 floats -> 4 OCP e4m3 bytes in one dword
__device__ __forceinline__ unsigned int pk_fp8x4(float a, float b, float c, float d) {
    int v = __builtin_amdgcn_cvt_pk_fp8_f32(a, b, 0, false);   // bytes 0,1
    v = __builtin_amdgcn_cvt_pk_fp8_f32(c, d, v, true);        // bytes 2,3
    return (unsigned int)v;
}

// two b128 LDS reads -> one v8i32 MX fragment (32 fp8 bytes / lane)
__device__ __forceinline__ i32x8 ld_frag(const unsigned char* rowbase, int lo, int hi) {
    i32x4 L = *(const i32x4*)(rowbase + lo);
    i32x4 H = *(const i32x4*)(rowbase + hi);
    i32x8 r;
    r[0] = L[0]; r[1] = L[1]; r[2] = L[2]; r[3] = L[3];
    r[4] = H[0]; r[5] = H[1]; r[6] = H[2]; r[7] = H[3];
    return r;
}

// MX-scaled fp8 MFMA, scales fixed at e8m0 0x7F = 2^0 = 1.0 (exact fp8 product,
// 2x the non-scaled fp8 rate). fmtA=fmtB=0 (OCP e4m3). Validated r21 (passed).
#define MXMFMA(AF, BF, ACC) ACC = __builtin_amdgcn_mfma_scale_f32_32x32x64_f8f6f4( \
        AF, BF, ACC, 0, 0, 0, 0x7F7F7F7F, 0, 0x7F7F7F7F)

// ---------------------------------------------------------------------------
// Kernel 1: row norms + fp8 e4m3 normalized copy + zeroing of row_sum and the
// handshake cells. One wave per row. (unchanged — measured fine)
__global__ __launch_bounds__(256) void norm_kernel(const float* __restrict__ feat,
                                                   unsigned char* __restrict__ fn8,
                                                   float* __restrict__ row_sum,
                                                   unsigned int* __restrict__ done_cnt,
                                                   unsigned int* __restrict__ fin_cnt,
                                                   float* __restrict__ loss_acc) {
    const int w = threadIdx.x >> 6, lane = threadIdx.x & 63;
    const int row = blockIdx.x * 4 + w;
    if (blockIdx.x == 0 && threadIdx.x == 0) {
        *done_cnt = 0u;
        *fin_cnt = 0u;
        *loss_acc = 0.f;
    }
    const float4* src = (const float4*)(feat + (size_t)row * D_DIM);
    float4 v[4];
    float ss = 0.f;
#pragma unroll
    for (int t = 0; t < 4; ++t) {
        v[t] = src[lane + 64 * t];
        ss += v[t].x * v[t].x + v[t].y * v[t].y + v[t].z * v[t].z + v[t].w * v[t].w;
    }
#pragma unroll
    for (int off = 32; off; off >>= 1) ss += __shfl_xor(ss, off);
    float nrm = fmaxf(sqrtf(ss), 1e-8f);
    if (lane == 0) row_sum[row] = 0.f;
    const float inv = 1.0f / nrm;
    unsigned int* dst = (unsigned int*)(fn8 + (size_t)row * D_DIM);
#pragma unroll
    for (int t = 0; t < 4; ++t)
        dst[lane + 64 * t] = pk_fp8x4(v[t].x * inv, v[t].y * inv, v[t].z * inv, v[t].w * inv);
}

// ---------------------------------------------------------------------------
// Raw workgroup barrier WITHOUT the __syncthreads() vmcnt(0) drain.
#define BARRIER() do { asm volatile("" ::: "memory"); \
    __builtin_amdgcn_s_barrier();                      \
    asm volatile("" ::: "memory"); } while (0)

// ---------------------------------------------------------------------------
// Kernel 2 (r23): r22's issue-early/wait-late double-buffer schedule grafted
// onto r21's register-lean addressing (r22 regressed purely because VGPR
// 80->248 collapsed occupancy to ~1 block/CU — the schedule itself was never
// tested at proper residency):
//  * fragment/staging math BYTE-IDENTICAL to r21 (passed, VGPR 80):
//    single incremental pa/pb (+=128/kt), no pointer arrays
//  * #pragma unroll 1 on the kt loop — forbid the 8x body explosion
//  * As[2]/Bs[2] x 16KB = 64 KB LDS double buffer
//  * per kt: [stage kt+1 into buf^1] -> [16 ds_read + 8 MXMFMA from buf]
//    -> [vmcnt(0) + s_barrier]: the L2 round-trip of the staging loads is
//    covered by the ~700+ cyc compute phase instead of serializing before it
//  * race-free: reads of buf^1 (iteration kt-1's operands) are
//    register-complete before that iteration's end-barrier; staging lands
//    before its consumer via the end-of-step vmcnt(0)
//  * s_setprio(1) around the MFMA cluster (waves now have role diversity)
// Epilogue (32x32 C/D layout) + fence-free loss tail verbatim from r21.
__global__ __launch_bounds__(256) void simgemm_kernel(const unsigned char* __restrict__ fn8,
                                                      float* __restrict__ row_sum,
                                                      float* __restrict__ s_target,
                                                      unsigned int* __restrict__ done_cnt,
                                                      unsigned int* __restrict__ fin_cnt,
                                                      float* __restrict__ loss_acc,
                                                      float* __restrict__ out) {
    __shared__ __align__(16) unsigned char As[2][16 * 1024];   // 32 KiB
    __shared__ __align__(16) unsigned char Bs[2][16 * 1024];   // 32 KiB
    // triangular decode: t -> (I,J), I<=J
    const int t = blockIdx.x;
    int a = (int)((sqrtf(8.f * (float)t + 1.f) - 1.f) * 0.5f);
    while ((a + 1) * (a + 2) / 2 <= t) ++a;
    while (a * (a + 1) / 2 > t) --a;
    const int I = t - a * (a + 1) / 2;   // row-tile index (<= J)
    const int J = a;                     // col-tile index
    const int r0 = I * 128, c0 = J * 128;
    const bool isdiag = (I == J);
    const bool haspair = (J == I + 32);  // contains sim[i, i+4096] for rows in I

    const int tid = threadIdx.x;
    const int w = tid >> 6, lane = tid & 63;
    const int wr = (w >> 1) * 64;  // wave's row base within tile
    const int wc = (w & 1) * 64;   // wave's col base within tile

    // ---- staging addressing (r21-identical): wave w stages rows
    // [w*32, w*32+32); call i writes chunk i (rows i*8..i*8+7), lane l ->
    // row i*8 + (l>>3), phys unit l&7, pre-swizzled source unit (l&7)^(l>>3)
    const int srow = lane >> 3;                               // 0..7
    const int slog = ((lane & 7) ^ srow) * 16;                // pre-swizzled byte off
    const unsigned char* pa = fn8 + (size_t)(r0 + w * 32 + srow) * D_DIM + slog;
    const unsigned char* pb = fn8 + (size_t)(c0 + w * 32 + srow) * D_DIM + slog;

    // ---- fragment addressing (r21-identical) ----
    const int fr = lane & 31;      // row (A) / col (B) within 32-chunk
    const int h = lane >> 5;       // K-half owner
    const int fs = fr & 7;         // de-swizzle key
    const int ca0 = (((w >> 1) * 2 + 0) * 4096) + fr * 128;
    const int ca1 = (((w >> 1) * 2 + 1) * 4096) + fr * 128;
    const int cb0 = (((w & 1) * 2 + 0) * 4096) + fr * 128;
    const int cb1 = (((w & 1) * 2 + 1) * 4096) + fr * 128;

    f32x16 acc[2][2] = {};

    // ---- prologue: stage tile 0 into buf 0 ----
#pragma unroll
    for (int i = 0; i < 4; ++i) {
        async_ld16(pa + (size_t)i * 8 * D_DIM, &As[0][w * 4096 + i * 1024]);
        async_ld16(pb + (size_t)i * 8 * D_DIM, &Bs[0][w * 4096 + i * 1024]);
    }
    pa += 128; pb += 128;
    asm volatile("s_waitcnt vmcnt(0)" ::: "memory");
    BARRIER();

    int buf = 0;
#pragma unroll 1
    for (int kt = 0; kt < 8; ++kt) {
        // issue-early: stage tile kt+1 into buf^1 (its last reads were
        // register-complete before the barrier we just crossed)
        if (kt < 7) {
#pragma unroll
            for (int i = 0; i < 4; ++i) {
                async_ld16(pa + (size_t)i * 8 * D_DIM, &As[buf ^ 1][w * 4096 + i * 1024]);
                async_ld16(pb + (size_t)i * 8 * D_DIM, &Bs[buf ^ 1][w * 4096 + i * 1024]);
            }
            pa += 128; pb += 128;
        }
        // compute tile kt from buf (compiler manages lgkmcnt for ds->MFMA)
        const unsigned char* bA = &As[buf][0];
        const unsigned char* bB = &Bs[buf][0];
#pragma unroll
        for (int k64 = 0; k64 < 2; ++k64) {
            const int lo = ((4 * k64 + 2 * h) ^ fs) * 16;
            const int hi = ((4 * k64 + 2 * h + 1) ^ fs) * 16;
            i32x8 a0 = ld_frag(bA + ca0, lo, hi);
            i32x8 a1 = ld_frag(bA + ca1, lo, hi);
            i32x8 b0 = ld_frag(bB + cb0, lo, hi);
            i32x8 b1 = ld_frag(bB + cb1, lo, hi);
            __builtin_amdgcn_s_setprio(1);
            MXMFMA(a0, b0, acc[0][0]);
            MXMFMA(a0, b1, acc[0][1]);
            MXMFMA(a1, b0, acc[1][0]);
            MXMFMA(a1, b1, acc[1][1]);
            __builtin_amdgcn_s_setprio(0);
        }
        // wait-late: next tile's loads had the whole compute phase to land
        if (kt < 7) {
            asm volatile("s_waitcnt vmcnt(0)" ::: "memory");
            BARRIER();
        }
        buf ^= 1;
    }

    // ---- epilogue: e = exp(sim - M); rows-in-I sums + (I<J) cols-in-J sums ----
    // 32x32 C/D layout: col = c0 + wc + tj*32 + (lane&31),
    //                   row = r0 + wr + ti*32 + (reg&3) + 8*(reg>>2) + 4*h
    const int colL = lane & 31;
    float cs[2] = {0.f, 0.f};
#pragma unroll
    for (int ti = 0; ti < 2; ++ti) {
#pragma unroll
        for (int reg = 0; reg < 16; ++reg) {
            const int rowL = (reg & 3) + 8 * (reg >> 2) + 4 * h;
            const int grow = r0 + wr + ti * 32 + rowL;
            float s = 0.f;
#pragma unroll
            for (int tj = 0; tj < 2; ++tj) {
                const int gcol = c0 + wc + tj * 32 + colL;
                float sim = acc[ti][tj][reg] * INV_T;
                float e = __expf(sim - INV_T);
                if (isdiag && grow == gcol) e = 0.f;   // diagonal mask
                if (haspair && gcol == grow + HALF_N) {
                    __hip_atomic_store(&s_target[grow], sim, __ATOMIC_RELAXED,
                                       __HIP_MEMORY_SCOPE_AGENT);
                    __hip_atomic_store(&s_target[gcol], sim, __ATOMIC_RELAXED,
                                       __HIP_MEMORY_SCOPE_AGENT);
                }
                s += e;
                cs[tj] += e;
            }
            // row path: reduce across the 32 column-lanes of this h-group
            s += __shfl_xor(s, 1);
            s += __shfl_xor(s, 2);
            s += __shfl_xor(s, 4);
            s += __shfl_xor(s, 8);
            s += __shfl_xor(s, 16);
            if (colL == 0) atomicAdd(&row_sum[grow], s);
        }
    }
    if (!isdiag) {
        // col path: lane l holds 32 of the wave's 64 rows for its column;
        // pair with lane l^32 (other h) to complete, one atomic per column
#pragma unroll
        for (int tj = 0; tj < 2; ++tj) {
            float s = cs[tj] + __shfl_xor(cs[tj], 32);
            if (h == 0) atomicAdd(&row_sum[c0 + wc + tj * 32 + colL], s);
        }
    }

    // ---- fence-free fused loss tail, 8-way parallel ----
    __syncthreads();   // all waves' vmem drained (compiler emits vmcnt(0) here)
    __shared__ unsigned int my_ord;
    if (tid == 0)
        my_ord = __hip_atomic_fetch_add(done_cnt, 1u, __ATOMIC_RELAXED,
                                        __HIP_MEMORY_SCOPE_AGENT);
    __syncthreads();
    const unsigned int ord = my_ord;
    if (ord >= N_TILES - N_RED) {
        // wait until ALL 2080 blocks have signalled (their sums are in).
        if (tid == 0) {
            while (__hip_atomic_load(done_cnt, __ATOMIC_RELAXED,
                                     __HIP_MEMORY_SCOPE_AGENT) < N_TILES)
                __builtin_amdgcn_s_sleep(1);
        }
        __syncthreads();
        const int slice = (int)(ord - (N_TILES - N_RED));   // 0..7
        const int base_row = slice * (N_ROWS / N_RED) + tid * 4;
        float rv[4], sv[4];
#pragma unroll
        for (int u = 0; u < 4; ++u) {
            rv[u] = __hip_atomic_load(&row_sum[base_row + u], __ATOMIC_RELAXED,
                                      __HIP_MEMORY_SCOPE_AGENT);
            sv[u] = __hip_atomic_load(&s_target[base_row + u], __ATOMIC_RELAXED,
                                      __HIP_MEMORY_SCOPE_AGENT);
        }
        float local = 0.f;
#pragma unroll
        for (int u = 0; u < 4; ++u)
            local += __logf(rv[u]) - sv[u];
#pragma unroll
        for (int off = 32; off; off >>= 1) local += __shfl_xor(local, off);
        __shared__ float part[4];
        if ((tid & 63) == 0) part[tid >> 6] = local;
        __syncthreads();
        if (tid == 0) {
            float bsum = part[0] + part[1] + part[2] + part[3];
            __hip_atomic_fetch_add(loss_acc, bsum, __ATOMIC_RELAXED,
                                   __HIP_MEMORY_SCOPE_AGENT);
            unsigned int f = __hip_atomic_fetch_add(fin_cnt, 1u, __ATOMIC_ACQ_REL,
                                                    __HIP_MEMORY_SCOPE_AGENT);
            if (f == N_RED - 1) {
                float accv = __hip_atomic_load(loss_acc, __ATOMIC_RELAXED,
                                               __HIP_MEMORY_SCOPE_AGENT);
                out[0] = INV_T + accv * (1.0f / N_ROWS);
            }
        }
    }
}

// ---------------------------------------------------------------------------
extern "C" void kernel_launch(void* const* d_in, const int* in_sizes, int n_in,
                              void* d_out, int out_size, void* d_ws, size_t ws_size,
                              hipStream_t stream) {
    const float* feat = (const float*)d_in[0];
    float* out = (float*)d_out;
    char* ws = (char*)d_ws;

    unsigned char* fn8 = (unsigned char*)ws;                  // 8192*1024 fp8 = 8 MiB
    size_t off = (size_t)N_ROWS * D_DIM;
    float* row_sum = (float*)(ws + off);   off += N_ROWS * sizeof(float);
    float* s_target = (float*)(ws + off);  off += N_ROWS * sizeof(float);
    unsigned int* done_cnt = (unsigned int*)(ws + off);  off += sizeof(unsigned int);
    unsigned int* fin_cnt = (unsigned int*)(ws + off);   off += sizeof(unsigned int);
    float* loss_acc = (float*)(ws + off);

    norm_kernel<<<N_ROWS / 4, 256, 0, stream>>>(feat, fn8, row_sum, done_cnt, fin_cnt, loss_acc);
    simgemm_kernel<<<N_TILES, 256, 0, stream>>>(fn8, row_sum, s_target, done_cnt, fin_cnt, loss_acc, out);
}